// Round 7
// baseline (1769.779 us; speedup 1.0000x reference)
//
#include <hip/hip_runtime.h>
#include <math.h>

#define D_  512
#define A_  64
#define B_  32
#define SE_ 1024
#define SD_ 256
#define V_  32000

static constexpr float SCALE_ = 0.044194173824159216f; // 1/sqrt(512)
static constexpr float SQRTD_ = 22.62741699796952f;    // sqrt(512)
static constexpr float EPS_   = 1e-6f;

typedef float f2 __attribute__((ext_vector_type(2)));
__device__ __forceinline__ f2 mkf2(float a, float b){ f2 r; r.x=a; r.y=b; return r; }
__device__ __forceinline__ f2 fma2(f2 a, f2 b, f2 c){ return __builtin_elementwise_fma(a,b,c); }

// ---- wave64 reductions via DPP (row_shr prefix + row_bcast), result broadcast via readlane(63)
__device__ __forceinline__ float wred_sum(float x){
  x += __int_as_float(__builtin_amdgcn_update_dpp(0, __float_as_int(x), 0x111, 0xf, 0xf, false));
  x += __int_as_float(__builtin_amdgcn_update_dpp(0, __float_as_int(x), 0x112, 0xf, 0xf, false));
  x += __int_as_float(__builtin_amdgcn_update_dpp(0, __float_as_int(x), 0x114, 0xf, 0xf, false));
  x += __int_as_float(__builtin_amdgcn_update_dpp(0, __float_as_int(x), 0x118, 0xf, 0xf, false));
  x += __int_as_float(__builtin_amdgcn_update_dpp(0, __float_as_int(x), 0x142, 0xa, 0xf, false));
  x += __int_as_float(__builtin_amdgcn_update_dpp(0, __float_as_int(x), 0x143, 0xc, 0xf, false));
  return __int_as_float(__builtin_amdgcn_readlane(__float_as_int(x), 63));
}
__device__ __forceinline__ float wred_max(float x){
  const int NI = 0xff800000; // -inf
  x = fmaxf(x, __int_as_float(__builtin_amdgcn_update_dpp(NI, __float_as_int(x), 0x111, 0xf, 0xf, false)));
  x = fmaxf(x, __int_as_float(__builtin_amdgcn_update_dpp(NI, __float_as_int(x), 0x112, 0xf, 0xf, false)));
  x = fmaxf(x, __int_as_float(__builtin_amdgcn_update_dpp(NI, __float_as_int(x), 0x114, 0xf, 0xf, false)));
  x = fmaxf(x, __int_as_float(__builtin_amdgcn_update_dpp(NI, __float_as_int(x), 0x118, 0xf, 0xf, false)));
  x = fmaxf(x, __int_as_float(__builtin_amdgcn_update_dpp(NI, __float_as_int(x), 0x142, 0xa, 0xf, false)));
  x = fmaxf(x, __int_as_float(__builtin_amdgcn_update_dpp(NI, __float_as_int(x), 0x143, 0xc, 0xf, false)));
  return __int_as_float(__builtin_amdgcn_readlane(__float_as_int(x), 63));
}

// Qa[a,d'] = sum_c encK[a,c]*Wq[d',c] + bq[d']
__global__ void k_qa(const float* __restrict__ Kw, const float* __restrict__ Wq,
                     const float* __restrict__ bq, float* __restrict__ qa){
  int a = blockIdx.x, d = threadIdx.x;
  const float4* kr = (const float4*)(Kw + (size_t)a*D_);
  const float4* wr = (const float4*)(Wq + (size_t)d*D_);
  float acc = 0.f;
  for(int c=0;c<128;c++){
    float4 kv = kr[c]; float4 wv = wr[c];
    acc += kv.x*wv.x + kv.y*wv.y + kv.z*wv.z + kv.w*wv.w;
  }
  qa[a*D_ + d] = acc + bq[d];
}

// weffA[a][c] = sum_d' qa[a,d']*Wk[d',c];  beff[a] = sum_d' qa[a,d']*bk[d']
__global__ void k_weff(const float* __restrict__ qa, const float* __restrict__ Wk,
                       const float* __restrict__ bk, float* __restrict__ weffA,
                       float* __restrict__ beff){
  int ec = blockIdx.x; int tid = threadIdx.x; int i = tid>>6, a = tid&63;
  int e = ec*8 + i;
  const float4* q4 = (const float4*)(qa + (size_t)a*D_);
  float acc=0.f;
  for(int c=0;c<128;c++){
    float4 qv = q4[c];
    int dp = c*4;
    acc += qv.x*Wk[(size_t)(dp+0)*D_+e] + qv.y*Wk[(size_t)(dp+1)*D_+e]
         + qv.z*Wk[(size_t)(dp+2)*D_+e] + qv.w*Wk[(size_t)(dp+3)*D_+e];
  }
  weffA[(size_t)a*D_ + e] = acc;
  if(ec==0 && i==0){
    const float4* b4 = (const float4*)bk;
    float acc2=0.f;
    for(int c=0;c<128;c++){
      float4 qv=q4[c]; float4 bv=b4[c];
      acc2 += qv.x*bv.x + qv.y*bv.y + qv.z*bv.z + qv.w*bv.w;
    }
    beff[a] = acc2;
  }
}

// parallel embedding gather: x_all[t][b][d] = emb[seq[b][t]][d] * sqrt(D)
__global__ __launch_bounds__(256) void k_emb(const int* __restrict__ seq,
                     const float* __restrict__ emb, float* __restrict__ zx){
  int w = threadIdx.x >> 6, l = threadIdx.x & 63;
  int r = blockIdx.x*4 + w;            // r = t*B + b
  int t = r >> 5, b = r & 31;
  int tok = seq[b*SE_ + t];
  const float4* src = (const float4*)(emb + (size_t)tok*D_ + l*8);
  float4 v0 = src[0], v1 = src[1];
  v0.x*=SQRTD_; v0.y*=SQRTD_; v0.z*=SQRTD_; v0.w*=SQRTD_;
  v1.x*=SQRTD_; v1.y*=SQRTD_; v1.z*=SQRTD_; v1.w*=SQRTD_;
  float4* dst = (float4*)(zx + (size_t)r*D_ + l*8);
  dst[0] = v0; dst[1] = v1;
}

// ============================================================================
// FUSED z -> gate -> av pipeline. UNIFORM-BARRIER version (fix for R4/R6 hangs:
// __syncthreads now sits in uniform control flow — a single textual barrier
// executed by ALL waves each iteration; divergent producer/consumer work
// happens between barriers).
// Block = 320 threads = 5 waves, handles (b, 4 consecutive a's).
//   wave 4 : producer — serial z-chain for b (duplicated across the 16 blocks
//            of the same b; latency-bound so duplication is ~free; same-b
//            blocks are ≡ b (mod 8) → same XCD, x re-reads are L2-served).
//   waves 0-3 : consumers — one a-chain each: gate (dot+wred+sigmoid) + av LN.
// Grid 512 → 2 independent blocks per CU: cross-block TLP fills barrier and
// dependency shadows.
// Iter it: producer fills zbuf[it&1] (4 steps); consumers process zbuf[(it-1)&1].
// Lane map everywhere: lane l owns dims [4l..4l+3] and [256+4l..256+4l+3].
// ============================================================================
__global__ __launch_bounds__(320) void k_zav(const float* __restrict__ x_all,
                      const float* __restrict__ weffA, const float* __restrict__ beffv,
                      const float* __restrict__ g1v, const float* __restrict__ b1v,
                      float* __restrict__ av_out, float* __restrict__ z_last){
  __shared__ __align__(16) float zbuf[2][4][D_];   // 2 x 4 steps x 512 = 16KB
  int tid = threadIdx.x;
  int l = tid & 63, w = tid >> 6;
  int b = blockIdx.x & 31;
  bool isProd = (w == 4);

  // LN params (same for both roles)
  f2 g2[4], b2[4];
  g2[0]=mkf2(g1v[4*l+0],g1v[4*l+1]);         b2[0]=mkf2(b1v[4*l+0],b1v[4*l+1]);
  g2[1]=mkf2(g1v[4*l+2],g1v[4*l+3]);         b2[1]=mkf2(b1v[4*l+2],b1v[4*l+3]);
  g2[2]=mkf2(g1v[256+4*l+0],g1v[256+4*l+1]); b2[2]=mkf2(b1v[256+4*l+0],b1v[256+4*l+1]);
  g2[3]=mkf2(g1v[256+4*l+2],g1v[256+4*l+3]); b2[3]=mkf2(b1v[256+4*l+2],b1v[256+4*l+3]);

  // producer state
  f2 z2[4];
  float4 XA[4][2], XB[4][2];
  const float* xb = x_all + (size_t)b*D_;
  // consumer state (index clamped for the producer wave; unused there)
  int a = (blockIdx.x >> 5)*4 + (isProd ? 0 : w);
  f2 av2[4], wf2[4];
  const float* wrow = weffA + (size_t)a*D_;
  wf2[0]=mkf2(wrow[4*l+0],wrow[4*l+1]);         wf2[1]=mkf2(wrow[4*l+2],wrow[4*l+3]);
  wf2[2]=mkf2(wrow[256+4*l+0],wrow[256+4*l+1]); wf2[3]=mkf2(wrow[256+4*l+2],wrow[256+4*l+3]);
  float be = beffv[a];
#pragma unroll
  for(int j=0;j<4;j++){ z2[j]=mkf2(0.f,0.f); av2[j]=mkf2(0.f,0.f); }

#define LOADX(buf, g) { int gc_ = ((g)<256)?(g):255; _Pragma("unroll") \
  for(int u=0;u<4;u++){ const float* p = xb + (size_t)(gc_*4+u)*(B_*D_); \
    buf[u][0]=*(const float4*)(p+4*l); buf[u][1]=*(const float4*)(p+256+4*l);} }

#define PZSTEP(xv, s, u) { \
  f2 y0 = z2[0] + mkf2(xv[0].x, xv[0].y); \
  f2 y1 = z2[1] + mkf2(xv[0].z, xv[0].w); \
  f2 y2_ = z2[2] + mkf2(xv[1].x, xv[1].y); \
  f2 y3 = z2[3] + mkf2(xv[1].z, xv[1].w); \
  f2 sv = (y0+y1)+(y2_+y3); \
  f2 ssv = fma2(y0,y0, fma2(y1,y1, fma2(y2_,y2_, y3*y3))); \
  float s_ = wred_sum(sv.x+sv.y); \
  float ss = wred_sum(ssv.x+ssv.y); \
  float m = s_*(1.f/512.f); \
  float var = fmaf(-m, s_, ss)*(1.f/511.f); \
  float inv = __builtin_amdgcn_rcpf(sqrtf(var)+EPS_); \
  float c2 = -m*inv; \
  f2 inv2 = mkf2(inv,inv), c22 = mkf2(c2,c2); \
  z2[0]=fma2(g2[0], fma2(inv2,y0 ,c22), b2[0]); \
  z2[1]=fma2(g2[1], fma2(inv2,y1 ,c22), b2[1]); \
  z2[2]=fma2(g2[2], fma2(inv2,y2_,c22), b2[2]); \
  z2[3]=fma2(g2[3], fma2(inv2,y3 ,c22), b2[3]); \
  *(float4*)&zbuf[s][u][4*l]     = make_float4(z2[0].x,z2[0].y,z2[1].x,z2[1].y); \
  *(float4*)&zbuf[s][u][256+4*l] = make_float4(z2[2].x,z2[2].y,z2[3].x,z2[3].y); }

#define AVSTEP3(za, zc, gte) { \
  f2 gte2 = mkf2(gte, gte); \
  f2 y0 = fma2(gte2, mkf2(za.x,za.y)-av2[0], av2[0]); \
  f2 y1 = fma2(gte2, mkf2(za.z,za.w)-av2[1], av2[1]); \
  f2 y2_ = fma2(gte2, mkf2(zc.x,zc.y)-av2[2], av2[2]); \
  f2 y3 = fma2(gte2, mkf2(zc.z,zc.w)-av2[3], av2[3]); \
  f2 sv = (y0+y1)+(y2_+y3); \
  f2 ssv = fma2(y0,y0, fma2(y1,y1, fma2(y2_,y2_, y3*y3))); \
  float s_ = wred_sum(sv.x+sv.y); \
  float ss = wred_sum(ssv.x+ssv.y); \
  float m = s_*(1.f/512.f); \
  float var = fmaf(-m, s_, ss)*(1.f/511.f); \
  float inv = __builtin_amdgcn_rcpf(sqrtf(var)+EPS_); \
  float c2 = -m*inv; \
  f2 inv2 = mkf2(inv,inv), c22 = mkf2(c2,c2); \
  av2[0]=fma2(g2[0], fma2(inv2,y0 ,c22), b2[0]); \
  av2[1]=fma2(g2[1], fma2(inv2,y1 ,c22), b2[1]); \
  av2[2]=fma2(g2[2], fma2(inv2,y2_,c22), b2[2]); \
  av2[3]=fma2(g2[3], fma2(inv2,y3 ,c22), b2[3]); \
}

  if(isProd){ LOADX(XA, 0); }

  for(int it=0; it<257; ++it){
    if(isProd){
      if(it < 256){
        int g = it, s = g & 1;
        if(g & 1){
          LOADX(XA, g+1);
          PZSTEP(XB[0],s,0); PZSTEP(XB[1],s,1); PZSTEP(XB[2],s,2); PZSTEP(XB[3],s,3);
        } else {
          LOADX(XB, g+1);
          PZSTEP(XA[0],s,0); PZSTEP(XA[1],s,1); PZSTEP(XA[2],s,2); PZSTEP(XA[3],s,3);
        }
      }
    } else {
      if(it >= 1){
        int g = it - 1, s = g & 1;
        float4 za[4], zc[4];
#pragma unroll
        for(int u=0;u<4;u++){
          za[u] = *(const float4*)&zbuf[s][u][4*l];
          zc[u] = *(const float4*)&zbuf[s][u][256+4*l];
        }
        // gates for the 4 steps (independent wred chains, pipeline together)
        float p[4];
#pragma unroll
        for(int u=0;u<4;u++){
          f2 acc = fma2(mkf2(za[u].x,za[u].y), wf2[0],
                   fma2(mkf2(za[u].z,za[u].w), wf2[1],
                   fma2(mkf2(zc[u].x,zc[u].y), wf2[2],
                        mkf2(zc[u].z,zc[u].w)*wf2[3])));
          p[u] = acc.x + acc.y;
        }
#pragma unroll
        for(int u=0;u<4;u++) p[u] = wred_sum(p[u]);
        float gte[4];
#pragma unroll
        for(int u=0;u<4;u++) gte[u] = __builtin_amdgcn_rcpf(1.f + __expf(-SCALE_*(p[u]+be)));
        AVSTEP3(za[0],zc[0],gte[0]); AVSTEP3(za[1],zc[1],gte[1]);
        AVSTEP3(za[2],zc[2],gte[2]); AVSTEP3(za[3],zc[3],gte[3]);
      }
    }
    __syncthreads();   // single textual barrier, uniform control flow
  }
#undef LOADX
#undef PZSTEP
#undef AVSTEP3

  if(isProd){
    // final z -> z_last for the decoder (16 identical redundant writes, benign)
    *(float4*)(z_last + (size_t)b*D_ + 4*l)       = make_float4(z2[0].x,z2[0].y,z2[1].x,z2[1].y);
    *(float4*)(z_last + (size_t)b*D_ + 256 + 4*l) = make_float4(z2[2].x,z2[2].y,z2[3].x,z2[3].y);
  } else {
    float* o = av_out + ((size_t)(b*A_+a))*D_;
    *(float4*)(o + 4*l)       = make_float4(av2[0].x,av2[0].y,av2[1].x,av2[1].y);
    *(float4*)(o + 256 + 4*l) = make_float4(av2[2].x,av2[2].y,av2[3].x,av2[3].y);
  }
}

// generic f32 GEMM: C[M,N] = A[M,512] @ W[N,512]^T + bias
__global__ __launch_bounds__(256) void k_gemm(const float* __restrict__ Amat,
                        const float* __restrict__ Wmat,
                        const float* __restrict__ bias, float* __restrict__ C,
                        int M, int N){
  __shared__ float As[32][64];
  __shared__ float Ws[32][64];
  int tid = threadIdx.x;
  int n0 = blockIdx.x*64, m0 = blockIdx.y*64;
  int tn = tid & 15, tm = tid >> 4;
  float acc[4][4];
#pragma unroll
  for(int i=0;i<4;i++)
#pragma unroll
    for(int j=0;j<4;j++) acc[i][j]=0.f;
  int lrow = tid >> 3;
  int lk = (tid & 7) * 4;
  for(int k0=0;k0<512;k0+=32){
#pragma unroll
    for(int p=0;p<2;p++){
      int row = p*32 + lrow;
      int m = m0 + row;
      float4 v = (m < M) ? *(const float4*)(Amat + (size_t)m*512 + k0 + lk) : make_float4(0,0,0,0);
      As[lk+0][row]=v.x; As[lk+1][row]=v.y; As[lk+2][row]=v.z; As[lk+3][row]=v.w;
      int n = n0 + row;
      float4 u = (n < N) ? *(const float4*)(Wmat + (size_t)n*512 + k0 + lk) : make_float4(0,0,0,0);
      Ws[lk+0][row]=u.x; Ws[lk+1][row]=u.y; Ws[lk+2][row]=u.z; Ws[lk+3][row]=u.w;
    }
    __syncthreads();
#pragma unroll
    for(int k=0;k<32;k++){
      float4 avv = *(const float4*)&As[k][tm*4];
      float4 wvv = *(const float4*)&Ws[k][tn*4];
      float a4[4]={avv.x,avv.y,avv.z,avv.w};
      float w4[4]={wvv.x,wvv.y,wvv.z,wvv.w};
#pragma unroll
      for(int i=0;i<4;i++)
#pragma unroll
        for(int j=0;j<4;j++) acc[i][j] += a4[i]*w4[j];
    }
    __syncthreads();
  }
#pragma unroll
  for(int i=0;i<4;i++){
    int m = m0 + tm*4 + i;
#pragma unroll
    for(int j=0;j<4;j++){
      int n = n0 + tn*4 + j;
      if(m<M && n<N) C[(size_t)m*N+n] = acc[i][j] + (bias ? bias[n] : 0.f);
    }
  }
}

// gT[b][e][a] = sum_d' Wq[d',e]*kr[b,a,d'];  cst[b,a] = sum_d' bq[d']*kr[b,a,d']
__global__ void k_gT(const float* __restrict__ Wq, const float* __restrict__ bq,
                     const float* __restrict__ kr, float* __restrict__ gT,
                     float* __restrict__ cst){
  int ec = blockIdx.x, b = blockIdx.y;
  int tid = threadIdx.x; int i = tid>>6, a = tid&63;
  int e = ec*8 + i;
  const float4* k4 = (const float4*)(kr + ((size_t)(b*A_+a))*D_);
  float acc=0.f;
  for(int c=0;c<128;c++){
    float4 kv = k4[c]; int dp = c*4;
    acc += kv.x*Wq[(size_t)(dp+0)*D_+e] + kv.y*Wq[(size_t)(dp+1)*D_+e]
         + kv.z*Wq[(size_t)(dp+2)*D_+e] + kv.w*Wq[(size_t)(dp+3)*D_+e];
  }
  gT[(size_t)b*D_*A_ + e*A_ + a] = acc;
  if(ec==0 && i==0){
    const float4* b4 = (const float4*)bq;
    float acc2=0.f;
    for(int c=0;c<128;c++){
      float4 kv=k4[c]; float4 bv=b4[c];
      acc2 += kv.x*bv.x+kv.y*bv.y+kv.z*bv.z+kv.w*bv.w;
    }
    cst[b*A_+a] = acc2;
  }
}

// decode: one block (512 thr) per batch; 2 barriers/step; packed-f32 dot products
__global__ __launch_bounds__(512) void k_dec(const float* __restrict__ gT,
                     const float* __restrict__ cstv, const float* __restrict__ vrw,
                     const float* __restrict__ zlast,
                     const float* __restrict__ n2g, const float* __restrict__ n2b,
                     float* __restrict__ zfin){
  int b = blockIdx.x; int tid = threadIdx.x; int w = tid>>6, lane = tid&63;
  __shared__ __align__(16) float zslot[512];
  __shared__ __align__(16) float part[512];
  __shared__ __align__(16) float attslot[512];
  __shared__ __align__(16) float2 redv[8];
  f2 G2[32], vr2[32];
  const float* gTb = gT + (size_t)b*D_*A_;
#pragma unroll
  for(int u=0;u<32;u++)
    G2[u] = mkf2(gTb[(size_t)(w*64+2*u)*A_ + lane], gTb[(size_t)(w*64+2*u+1)*A_ + lane]);
#pragma unroll
  for(int u=0;u<32;u++)
    vr2[u] = mkf2(vrw[((size_t)b*A_ + 2*u)*D_ + tid], vrw[((size_t)b*A_ + 2*u+1)*D_ + tid]);
  float cst = cstv[b*A_ + lane];
  float gg = n2g[tid], bb = n2b[tid];
  float z = zlast[(size_t)b*D_ + tid];
  for(int t=0;t<SD_;t++){
    zslot[tid] = z;
    f2 pA = mkf2(0.f,0.f), pB = mkf2(0.f,0.f);
    const float4* z4 = (const float4*)(zslot + w*64);
#pragma unroll
    for(int j=0;j<16;j++){ float4 zz = z4[j];
      pA = fma2(mkf2(zz.x,zz.y), G2[2*j+0], pA);
      pB = fma2(mkf2(zz.z,zz.w), G2[2*j+1], pB); }
    { f2 pt = pA + pB; part[tid] = pt.x + pt.y; }
    __syncthreads();                       // barrier 1: score partials
    float s = (((part[0*64+lane]+part[1*64+lane]) + (part[2*64+lane]+part[3*64+lane]))
             + ((part[4*64+lane]+part[5*64+lane]) + (part[6*64+lane]+part[7*64+lane]))) + cst;
    s *= SCALE_;
    float mx = wred_max(s);
    float e = __expf(s - mx);
    float su = wred_sum(e);
    float att = e * __builtin_amdgcn_rcpf(su);
    attslot[tid] = att;                    // own-wave slot, no barrier
    f2 dA = mkf2(0.f,0.f), dB = mkf2(0.f,0.f);
    const float4* at4 = (const float4*)(attslot + w*64);
#pragma unroll
    for(int j=0;j<16;j++){ float4 aa = at4[j];
      dA = fma2(mkf2(aa.x,aa.y), vr2[2*j+0], dA);
      dB = fma2(mkf2(aa.z,aa.w), vr2[2*j+1], dB); }
    f2 dt = dA + dB;
    float dg = dt.x + dt.y;
    float y = z + dg;
    float s1 = wred_sum(y);
    float s2 = wred_sum(y*y);
    if(lane==0) redv[w] = make_float2(s1, s2);
    __syncthreads();                       // barrier 2: LN partials
    float S=0.f, SS=0.f;
    const float4* r4 = (const float4*)redv;
#pragma unroll
    for(int q=0;q<4;q++){ float4 rr = r4[q]; S += rr.x + rr.z; SS += rr.y + rr.w; }
    float m = S*(1.f/512.f);
    float var = (SS - S*m)*(1.f/511.f);
    float inv = __builtin_amdgcn_rcpf(sqrtf(var)+EPS_);
    z = gg*((y-m)*inv) + bb;
  }
  zfin[(size_t)b*D_ + tid] = z;
}

__global__ void k_lsm(float* __restrict__ out){
  int b = blockIdx.x; float* row = out + (size_t)b*V_;
  __shared__ float sm[16];
  int tid = threadIdx.x, lane = tid&63, wid = tid>>6;
  float mx = -3.0e38f;
  for(int i=tid;i<V_;i+=1024) mx = fmaxf(mx, row[i]);
  mx = wred_max(mx);
  if(lane==0) sm[wid] = mx;
  __syncthreads();
  float M = sm[0];
#pragma unroll
  for(int q=1;q<16;q++) M = fmaxf(M, sm[q]);
  __syncthreads();
  float s=0.f;
  for(int i=tid;i<V_;i+=1024) s += __expf(row[i]-M);
  s = wred_sum(s);
  if(lane==0) sm[wid] = s;
  __syncthreads();
  float S=0.f;
#pragma unroll
  for(int q=0;q<16;q++) S += sm[q];
  float L = M + logf(S);
  for(int i=tid;i<V_;i+=1024) row[i] -= L;
}

extern "C" void kernel_launch(void* const* d_in, const int* in_sizes, int n_in,
                              void* d_out, int out_size, void* d_ws, size_t ws_size,
                              hipStream_t stream) {
  (void)in_sizes; (void)n_in; (void)out_size; (void)ws_size;
  const int*   seq  = (const int*)d_in[0];
  const float* emb  = (const float*)d_in[2];
  const float* encK = (const float*)d_in[4];
  const float* eWq  = (const float*)d_in[5];
  const float* ebq  = (const float*)d_in[6];
  const float* eWk  = (const float*)d_in[7];
  const float* ebk  = (const float*)d_in[8];
  const float* n1g  = (const float*)d_in[9];
  const float* n1b  = (const float*)d_in[10];
  const float* rWq  = (const float*)d_in[12];
  const float* rbq  = (const float*)d_in[13];
  const float* rWk  = (const float*)d_in[14];
  const float* rbk  = (const float*)d_in[15];
  const float* rWv  = (const float*)d_in[16];
  const float* rbv  = (const float*)d_in[17];
  const float* n2g  = (const float*)d_in[22];
  const float* n2b  = (const float*)d_in[23];
  const float* vW   = (const float*)d_in[26];
  const float* vb   = (const float*)d_in[27];

  float* ws    = (float*)d_ws;
  float* x_all = ws;                                    // 16,777,216 (emb gather)
  float* av    = x_all + (size_t)SE_*B_*D_;             //  1,048,576
  float* qa    = av    + (size_t)B_*A_*D_;              //     32,768
  float* weffA = qa    + (size_t)A_*D_;                 //     32,768
  float* beff  = weffA + (size_t)A_*D_;                 //         64
  float* kr    = beff  + A_;                            //  1,048,576
  float* vr    = kr    + (size_t)B_*A_*D_;              //  1,048,576
  float* gT    = vr    + (size_t)B_*A_*D_;              //  1,048,576
  float* cst   = gT    + (size_t)B_*D_*A_;              //      2,048
  float* zfin  = cst   + (size_t)B_*A_;                 //     16,384
  float* out   = (float*)d_out;
  // zlast aliases qa: qa is only read by k_weff (dispatch 2), dead afterwards.
  float* zlast = qa;

  k_qa   <<<dim3(A_),      dim3(D_),  0, stream>>>(encK, eWq, ebq, qa);
  k_weff <<<dim3(64),      dim3(512), 0, stream>>>(qa, eWk, ebk, weffA, beff);
  k_emb  <<<dim3(8192),    dim3(256), 0, stream>>>(seq, emb, x_all);
  k_zav  <<<dim3(512),     dim3(320), 0, stream>>>(x_all, weffA, beff, n1g, n1b, av, zlast);
  k_gemm <<<dim3(8,32),    dim3(256), 0, stream>>>(av, rWk, rbk, kr, B_*A_, D_);
  k_gemm <<<dim3(8,32),    dim3(256), 0, stream>>>(av, rWv, rbv, vr, B_*A_, D_);
  k_gT   <<<dim3(64,B_),   dim3(512), 0, stream>>>(rWq, rbq, kr, gT, cst);
  k_dec  <<<dim3(B_),      dim3(512), 0, stream>>>(gT, cst, vr, zlast, n2g, n2b, zfin);
  k_gemm <<<dim3(500,1),   dim3(256), 0, stream>>>(zfin, vW, vb, out, B_, V_);
  k_lsm  <<<dim3(B_),      dim3(1024),0, stream>>>(out);
}

// Round 8
// 1338.392 us; speedup vs baseline: 1.3223x; 1.3223x over previous
//
#include <hip/hip_runtime.h>
#include <math.h>

#define D_  512
#define A_  64
#define B_  32
#define SE_ 1024
#define SD_ 256
#define V_  32000

static constexpr float SCALE_ = 0.044194173824159216f; // 1/sqrt(512)
static constexpr float SQRTD_ = 22.62741699796952f;    // sqrt(512)
static constexpr float EPS_   = 1e-6f;

typedef float f2 __attribute__((ext_vector_type(2)));
__device__ __forceinline__ f2 mkf2(float a, float b){ f2 r; r.x=a; r.y=b; return r; }
__device__ __forceinline__ f2 fma2(f2 a, f2 b, f2 c){ return __builtin_elementwise_fma(a,b,c); }

// ---- wave64 reductions via DPP (row_shr prefix + row_bcast), result broadcast via readlane(63)
__device__ __forceinline__ float wred_sum(float x){
  x += __int_as_float(__builtin_amdgcn_update_dpp(0, __float_as_int(x), 0x111, 0xf, 0xf, false));
  x += __int_as_float(__builtin_amdgcn_update_dpp(0, __float_as_int(x), 0x112, 0xf, 0xf, false));
  x += __int_as_float(__builtin_amdgcn_update_dpp(0, __float_as_int(x), 0x114, 0xf, 0xf, false));
  x += __int_as_float(__builtin_amdgcn_update_dpp(0, __float_as_int(x), 0x118, 0xf, 0xf, false));
  x += __int_as_float(__builtin_amdgcn_update_dpp(0, __float_as_int(x), 0x142, 0xa, 0xf, false));
  x += __int_as_float(__builtin_amdgcn_update_dpp(0, __float_as_int(x), 0x143, 0xc, 0xf, false));
  return __int_as_float(__builtin_amdgcn_readlane(__float_as_int(x), 63));
}
__device__ __forceinline__ float wred_max(float x){
  const int NI = 0xff800000; // -inf
  x = fmaxf(x, __int_as_float(__builtin_amdgcn_update_dpp(NI, __float_as_int(x), 0x111, 0xf, 0xf, false)));
  x = fmaxf(x, __int_as_float(__builtin_amdgcn_update_dpp(NI, __float_as_int(x), 0x112, 0xf, 0xf, false)));
  x = fmaxf(x, __int_as_float(__builtin_amdgcn_update_dpp(NI, __float_as_int(x), 0x114, 0xf, 0xf, false)));
  x = fmaxf(x, __int_as_float(__builtin_amdgcn_update_dpp(NI, __float_as_int(x), 0x118, 0xf, 0xf, false)));
  x = fmaxf(x, __int_as_float(__builtin_amdgcn_update_dpp(NI, __float_as_int(x), 0x142, 0xa, 0xf, false)));
  x = fmaxf(x, __int_as_float(__builtin_amdgcn_update_dpp(NI, __float_as_int(x), 0x143, 0xc, 0xf, false)));
  return __int_as_float(__builtin_amdgcn_readlane(__float_as_int(x), 63));
}

// Qa[a,d'] = sum_c encK[a,c]*Wq[d',c] + bq[d']
__global__ void k_qa(const float* __restrict__ Kw, const float* __restrict__ Wq,
                     const float* __restrict__ bq, float* __restrict__ qa){
  int a = blockIdx.x, d = threadIdx.x;
  const float4* kr = (const float4*)(Kw + (size_t)a*D_);
  const float4* wr = (const float4*)(Wq + (size_t)d*D_);
  float acc = 0.f;
  for(int c=0;c<128;c++){
    float4 kv = kr[c]; float4 wv = wr[c];
    acc += kv.x*wv.x + kv.y*wv.y + kv.z*wv.z + kv.w*wv.w;
  }
  qa[a*D_ + d] = acc + bq[d];
}

// weffA[a][c] = sum_d' qa[a,d']*Wk[d',c];  beff[a] = sum_d' qa[a,d']*bk[d']
__global__ void k_weff(const float* __restrict__ qa, const float* __restrict__ Wk,
                       const float* __restrict__ bk, float* __restrict__ weffA,
                       float* __restrict__ beff){
  int ec = blockIdx.x; int tid = threadIdx.x; int i = tid>>6, a = tid&63;
  int e = ec*8 + i;
  const float4* q4 = (const float4*)(qa + (size_t)a*D_);
  float acc=0.f;
  for(int c=0;c<128;c++){
    float4 qv = q4[c];
    int dp = c*4;
    acc += qv.x*Wk[(size_t)(dp+0)*D_+e] + qv.y*Wk[(size_t)(dp+1)*D_+e]
         + qv.z*Wk[(size_t)(dp+2)*D_+e] + qv.w*Wk[(size_t)(dp+3)*D_+e];
  }
  weffA[(size_t)a*D_ + e] = acc;
  if(ec==0 && i==0){
    const float4* b4 = (const float4*)bk;
    float acc2=0.f;
    for(int c=0;c<128;c++){
      float4 qv=q4[c]; float4 bv=b4[c];
      acc2 += qv.x*bv.x + qv.y*bv.y + qv.z*bv.z + qv.w*bv.w;
    }
    beff[a] = acc2;
  }
}

// parallel embedding gather: x_all[t][b][d] = emb[seq[b][t]][d] * sqrt(D)
__global__ __launch_bounds__(256) void k_emb(const int* __restrict__ seq,
                     const float* __restrict__ emb, float* __restrict__ zx){
  int w = threadIdx.x >> 6, l = threadIdx.x & 63;
  int r = blockIdx.x*4 + w;            // r = t*B + b
  int t = r >> 5, b = r & 31;
  int tok = seq[b*SE_ + t];
  const float4* src = (const float4*)(emb + (size_t)tok*D_ + l*8);
  float4 v0 = src[0], v1 = src[1];
  v0.x*=SQRTD_; v0.y*=SQRTD_; v0.z*=SQRTD_; v0.w*=SQRTD_;
  v1.x*=SQRTD_; v1.y*=SQRTD_; v1.z*=SQRTD_; v1.w*=SQRTD_;
  float4* dst = (float4*)(zx + (size_t)r*D_ + l*8);
  dst[0] = v0; dst[1] = v1;
}

// ============================================================================
// FUSED z -> gate -> av pipeline, BARRIER-STEPPED (verified R5 version).
// Block = 576 threads = 9 waves, handles (b, 8 consecutive a's).
// ============================================================================
__global__ __launch_bounds__(576) void k_zav(const float* __restrict__ x_all,
                      const float* __restrict__ weffA, const float* __restrict__ beffv,
                      const float* __restrict__ g1v, const float* __restrict__ b1v,
                      float* __restrict__ av_out, float* __restrict__ z_last){
  __shared__ __align__(16) float zbuf[2][4][D_];   // 2 x 4 steps x 512 = 16KB
  int tid = threadIdx.x;
  int l = tid & 63, w = tid >> 6;
  int b = blockIdx.x & 31;

  if(w == 8){
    // ------------------------- producer: z-chain -------------------------
    f2 z2[4], g2[4], b2[4];
    g2[0]=mkf2(g1v[4*l+0],g1v[4*l+1]);         b2[0]=mkf2(b1v[4*l+0],b1v[4*l+1]);
    g2[1]=mkf2(g1v[4*l+2],g1v[4*l+3]);         b2[1]=mkf2(b1v[4*l+2],b1v[4*l+3]);
    g2[2]=mkf2(g1v[256+4*l+0],g1v[256+4*l+1]); b2[2]=mkf2(b1v[256+4*l+0],b1v[256+4*l+1]);
    g2[3]=mkf2(g1v[256+4*l+2],g1v[256+4*l+3]); b2[3]=mkf2(b1v[256+4*l+2],b1v[256+4*l+3]);
#pragma unroll
    for(int j=0;j<4;j++) z2[j]=mkf2(0.f,0.f);
    const float* xb = x_all + (size_t)b*D_;
    float4 XA[4][2], XB[4][2];

#define LOADX(buf, g) { int gc_ = ((g)<256)?(g):255; _Pragma("unroll") \
  for(int u=0;u<4;u++){ const float* p = xb + (size_t)(gc_*4+u)*(B_*D_); \
    buf[u][0]=*(const float4*)(p+4*l); buf[u][1]=*(const float4*)(p+256+4*l);} }

#define PZSTEP(xv, s, u) { \
  f2 y0 = z2[0] + mkf2(xv[0].x, xv[0].y); \
  f2 y1 = z2[1] + mkf2(xv[0].z, xv[0].w); \
  f2 y2_ = z2[2] + mkf2(xv[1].x, xv[1].y); \
  f2 y3 = z2[3] + mkf2(xv[1].z, xv[1].w); \
  f2 sv = (y0+y1)+(y2_+y3); \
  f2 ssv = fma2(y0,y0, fma2(y1,y1, fma2(y2_,y2_, y3*y3))); \
  float s_ = wred_sum(sv.x+sv.y); \
  float ss = wred_sum(ssv.x+ssv.y); \
  float m = s_*(1.f/512.f); \
  float var = fmaf(-m, s_, ss)*(1.f/511.f); \
  float inv = __builtin_amdgcn_rcpf(sqrtf(var)+EPS_); \
  float c2 = -m*inv; \
  f2 inv2 = mkf2(inv,inv), c22 = mkf2(c2,c2); \
  z2[0]=fma2(g2[0], fma2(inv2,y0 ,c22), b2[0]); \
  z2[1]=fma2(g2[1], fma2(inv2,y1 ,c22), b2[1]); \
  z2[2]=fma2(g2[2], fma2(inv2,y2_,c22), b2[2]); \
  z2[3]=fma2(g2[3], fma2(inv2,y3 ,c22), b2[3]); \
  *(float4*)&zbuf[s][u][4*l]     = make_float4(z2[0].x,z2[0].y,z2[1].x,z2[1].y); \
  *(float4*)&zbuf[s][u][256+4*l] = make_float4(z2[2].x,z2[2].y,z2[3].x,z2[3].y); }

    LOADX(XA, 0);
    for(int it=0; it<257; ++it){
      if(it < 256){
        int g = it, s = g & 1;
        if(g & 1){
          LOADX(XA, g+1);
          PZSTEP(XB[0],s,0); PZSTEP(XB[1],s,1); PZSTEP(XB[2],s,2); PZSTEP(XB[3],s,3);
        } else {
          LOADX(XB, g+1);
          PZSTEP(XA[0],s,0); PZSTEP(XA[1],s,1); PZSTEP(XA[2],s,2); PZSTEP(XA[3],s,3);
        }
      }
      __syncthreads();
    }
    // final z -> z_last for the decoder
    *(float4*)(z_last + (size_t)b*D_ + 4*l)       = make_float4(z2[0].x,z2[0].y,z2[1].x,z2[1].y);
    *(float4*)(z_last + (size_t)b*D_ + 256 + 4*l) = make_float4(z2[2].x,z2[2].y,z2[3].x,z2[3].y);
#undef LOADX
#undef PZSTEP
  } else {
    // --------------------- consumer: gate + av-chain ---------------------
    int a = (blockIdx.x >> 5)*8 + w;
    f2 av2[4], g2[4], b2[4], wf2[4];
    const float* wrow = weffA + (size_t)a*D_;
    g2[0]=mkf2(g1v[4*l+0],g1v[4*l+1]);         b2[0]=mkf2(b1v[4*l+0],b1v[4*l+1]);
    g2[1]=mkf2(g1v[4*l+2],g1v[4*l+3]);         b2[1]=mkf2(b1v[4*l+2],b1v[4*l+3]);
    g2[2]=mkf2(g1v[256+4*l+0],g1v[256+4*l+1]); b2[2]=mkf2(b1v[256+4*l+0],b1v[256+4*l+1]);
    g2[3]=mkf2(g1v[256+4*l+2],g1v[256+4*l+3]); b2[3]=mkf2(b1v[256+4*l+2],b1v[256+4*l+3]);
    wf2[0]=mkf2(wrow[4*l+0],wrow[4*l+1]);         wf2[1]=mkf2(wrow[4*l+2],wrow[4*l+3]);
    wf2[2]=mkf2(wrow[256+4*l+0],wrow[256+4*l+1]); wf2[3]=mkf2(wrow[256+4*l+2],wrow[256+4*l+3]);
#pragma unroll
    for(int j=0;j<4;j++) av2[j]=mkf2(0.f,0.f);
    float be = beffv[a];

#define AVSTEP3(za, zc, gte) { \
  f2 gte2 = mkf2(gte, gte); \
  f2 y0 = fma2(gte2, mkf2(za.x,za.y)-av2[0], av2[0]); \
  f2 y1 = fma2(gte2, mkf2(za.z,za.w)-av2[1], av2[1]); \
  f2 y2_ = fma2(gte2, mkf2(zc.x,zc.y)-av2[2], av2[2]); \
  f2 y3 = fma2(gte2, mkf2(zc.z,zc.w)-av2[3], av2[3]); \
  f2 sv = (y0+y1)+(y2_+y3); \
  f2 ssv = fma2(y0,y0, fma2(y1,y1, fma2(y2_,y2_, y3*y3))); \
  float s_ = wred_sum(sv.x+sv.y); \
  float ss = wred_sum(ssv.x+ssv.y); \
  float m = s_*(1.f/512.f); \
  float var = fmaf(-m, s_, ss)*(1.f/511.f); \
  float inv = __builtin_amdgcn_rcpf(sqrtf(var)+EPS_); \
  float c2 = -m*inv; \
  f2 inv2 = mkf2(inv,inv), c22 = mkf2(c2,c2); \
  av2[0]=fma2(g2[0], fma2(inv2,y0 ,c22), b2[0]); \
  av2[1]=fma2(g2[1], fma2(inv2,y1 ,c22), b2[1]); \
  av2[2]=fma2(g2[2], fma2(inv2,y2_,c22), b2[2]); \
  av2[3]=fma2(g2[3], fma2(inv2,y3 ,c22), b2[3]); \
}

    for(int it=0; it<257; ++it){
      if(it >= 1){
        int g = it - 1, s = g & 1;
        float4 za[4], zc[4];
#pragma unroll
        for(int u=0;u<4;u++){
          za[u] = *(const float4*)&zbuf[s][u][4*l];
          zc[u] = *(const float4*)&zbuf[s][u][256+4*l];
        }
        // gates for the 4 steps (independent wred chains, pipeline together)
        float p[4];
#pragma unroll
        for(int u=0;u<4;u++){
          f2 acc = fma2(mkf2(za[u].x,za[u].y), wf2[0],
                   fma2(mkf2(za[u].z,za[u].w), wf2[1],
                   fma2(mkf2(zc[u].x,zc[u].y), wf2[2],
                        mkf2(zc[u].z,zc[u].w)*wf2[3])));
          p[u] = acc.x + acc.y;
        }
#pragma unroll
        for(int u=0;u<4;u++) p[u] = wred_sum(p[u]);
        float gte[4];
#pragma unroll
        for(int u=0;u<4;u++) gte[u] = __builtin_amdgcn_rcpf(1.f + __expf(-SCALE_*(p[u]+be)));
        AVSTEP3(za[0],zc[0],gte[0]); AVSTEP3(za[1],zc[1],gte[1]);
        AVSTEP3(za[2],zc[2],gte[2]); AVSTEP3(za[3],zc[3],gte[3]);
      }
      __syncthreads();
    }
#undef AVSTEP3
    float* o = av_out + ((size_t)(b*A_+a))*D_;
    *(float4*)(o + 4*l)       = make_float4(av2[0].x,av2[0].y,av2[1].x,av2[1].y);
    *(float4*)(o + 256 + 4*l) = make_float4(av2[2].x,av2[2].y,av2[3].x,av2[3].y);
  }
}

// generic f32 GEMM: C[M,N] = A[M,512] @ W[N,512]^T + bias
__global__ __launch_bounds__(256) void k_gemm(const float* __restrict__ Amat,
                        const float* __restrict__ Wmat,
                        const float* __restrict__ bias, float* __restrict__ C,
                        int M, int N){
  __shared__ float As[32][64];
  __shared__ float Ws[32][64];
  int tid = threadIdx.x;
  int n0 = blockIdx.x*64, m0 = blockIdx.y*64;
  int tn = tid & 15, tm = tid >> 4;
  float acc[4][4];
#pragma unroll
  for(int i=0;i<4;i++)
#pragma unroll
    for(int j=0;j<4;j++) acc[i][j]=0.f;
  int lrow = tid >> 3;
  int lk = (tid & 7) * 4;
  for(int k0=0;k0<512;k0+=32){
#pragma unroll
    for(int p=0;p<2;p++){
      int row = p*32 + lrow;
      int m = m0 + row;
      float4 v = (m < M) ? *(const float4*)(Amat + (size_t)m*512 + k0 + lk) : make_float4(0,0,0,0);
      As[lk+0][row]=v.x; As[lk+1][row]=v.y; As[lk+2][row]=v.z; As[lk+3][row]=v.w;
      int n = n0 + row;
      float4 u = (n < N) ? *(const float4*)(Wmat + (size_t)n*512 + k0 + lk) : make_float4(0,0,0,0);
      Ws[lk+0][row]=u.x; Ws[lk+1][row]=u.y; Ws[lk+2][row]=u.z; Ws[lk+3][row]=u.w;
    }
    __syncthreads();
#pragma unroll
    for(int k=0;k<32;k++){
      float4 avv = *(const float4*)&As[k][tm*4];
      float4 wvv = *(const float4*)&Ws[k][tn*4];
      float a4[4]={avv.x,avv.y,avv.z,avv.w};
      float w4[4]={wvv.x,wvv.y,wvv.z,wvv.w};
#pragma unroll
      for(int i=0;i<4;i++)
#pragma unroll
        for(int j=0;j<4;j++) acc[i][j] += a4[i]*w4[j];
    }
    __syncthreads();
  }
#pragma unroll
  for(int i=0;i<4;i++){
    int m = m0 + tm*4 + i;
#pragma unroll
    for(int j=0;j<4;j++){
      int n = n0 + tn*4 + j;
      if(m<M && n<N) C[(size_t)m*N+n] = acc[i][j] + (bias ? bias[n] : 0.f);
    }
  }
}

// ============================================================================
// k_gT2: tiled GEMM for gT[b][e][a] = sum_d kr[b,a,d] * Wq[d,e]  (+ cst fold)
// C[a,e] = kr[b] (64x512) @ Wq (512x512, row-major, NOT transposed).
// Coalesced loads of both operands; transposed C-write is coalesced along a.
// cst[b,a] = bq . kr[b,a,:] computed by the e0==0 block (tid<64).
// ============================================================================
__global__ __launch_bounds__(256) void k_gT2(const float* __restrict__ Wq,
                     const float* __restrict__ bq, const float* __restrict__ kr,
                     float* __restrict__ gT, float* __restrict__ cst){
  __shared__ float As[32][64];   // [k][a]
  __shared__ float Ws[32][64];   // [k][e]
  int tid = threadIdx.x;
  int e0 = blockIdx.x*64; int b = blockIdx.y;
  int tn = tid & 15, tm = tid >> 4;
  const float* Ab = kr + (size_t)b*A_*D_;
  float acc[4][4];
#pragma unroll
  for(int i=0;i<4;i++)
#pragma unroll
    for(int j=0;j<4;j++) acc[i][j]=0.f;
  int lrow = tid >> 3;          // 0..31
  int lk   = (tid & 7) * 4;     // 0..28
  int wrow = tid >> 4;          // 0..15 (k for Wq loads)
  int wcol = (tid & 15) * 4;    // 0..60 (e offset)
  for(int k0=0;k0<512;k0+=32){
    // A-tile: As[k][a] from kr[b][a][k0+k] (row-major rows of 512)
#pragma unroll
    for(int p=0;p<2;p++){
      int row = p*32 + lrow;     // a
      float4 v = *(const float4*)(Ab + (size_t)row*D_ + k0 + lk);
      As[lk+0][row]=v.x; As[lk+1][row]=v.y; As[lk+2][row]=v.z; As[lk+3][row]=v.w;
    }
    // B-tile: Ws[k][e] from Wq[(k0+k)*512 + e0+e] — coalesced along e
#pragma unroll
    for(int p=0;p<2;p++){
      int k = p*16 + wrow;
      float4 u = *(const float4*)(Wq + (size_t)(k0+k)*D_ + e0 + wcol);
      *(float4*)&Ws[k][wcol] = u;
    }
    __syncthreads();
#pragma unroll
    for(int k=0;k<32;k++){
      float4 avv = *(const float4*)&As[k][tm*4];
      float4 wvv = *(const float4*)&Ws[k][tn*4];
      float a4[4]={avv.x,avv.y,avv.z,avv.w};
      float w4[4]={wvv.x,wvv.y,wvv.z,wvv.w};
#pragma unroll
      for(int i=0;i<4;i++)
#pragma unroll
        for(int j=0;j<4;j++) acc[i][j] = fmaf(a4[i], w4[j], acc[i][j]);
    }
    __syncthreads();
  }
  // write gT[b][e][a]: per j, a float4 along a (contiguous)
  float* gTb = gT + (size_t)b*D_*A_;
#pragma unroll
  for(int j=0;j<4;j++){
    int e = e0 + tn*4 + j;
    *(float4*)(gTb + (size_t)e*A_ + tm*4) =
        make_float4(acc[0][j], acc[1][j], acc[2][j], acc[3][j]);
  }
  // cst fold: one block per b computes bq . kr[b,a,:] for its 64 anchors
  if(blockIdx.x == 0 && tid < 64){
    const float4* k4 = (const float4*)(Ab + (size_t)tid*D_);
    const float4* b4 = (const float4*)bq;
    float acc2 = 0.f;
    for(int c=0;c<128;c++){
      float4 kv = k4[c], bv = b4[c];
      acc2 += kv.x*bv.x + kv.y*bv.y + kv.z*bv.z + kv.w*bv.w;
    }
    cst[b*A_ + tid] = acc2;
  }
}

// decode: one block (512 thr) per batch; 2 barriers/step; packed-f32 dot products
__global__ __launch_bounds__(512) void k_dec(const float* __restrict__ gT,
                     const float* __restrict__ cstv, const float* __restrict__ vrw,
                     const float* __restrict__ zlast,
                     const float* __restrict__ n2g, const float* __restrict__ n2b,
                     float* __restrict__ zfin){
  int b = blockIdx.x; int tid = threadIdx.x; int w = tid>>6, lane = tid&63;
  __shared__ __align__(16) float zslot[512];
  __shared__ __align__(16) float part[512];
  __shared__ __align__(16) float attslot[512];
  __shared__ __align__(16) float2 redv[8];
  f2 G2[32], vr2[32];
  const float* gTb = gT + (size_t)b*D_*A_;
#pragma unroll
  for(int u=0;u<32;u++)
    G2[u] = mkf2(gTb[(size_t)(w*64+2*u)*A_ + lane], gTb[(size_t)(w*64+2*u+1)*A_ + lane]);
#pragma unroll
  for(int u=0;u<32;u++)
    vr2[u] = mkf2(vrw[((size_t)b*A_ + 2*u)*D_ + tid], vrw[((size_t)b*A_ + 2*u+1)*D_ + tid]);
  float cst = cstv[b*A_ + lane];
  float gg = n2g[tid], bb = n2b[tid];
  float z = zlast[(size_t)b*D_ + tid];
  for(int t=0;t<SD_;t++){
    zslot[tid] = z;
    f2 pA = mkf2(0.f,0.f), pB = mkf2(0.f,0.f);
    const float4* z4 = (const float4*)(zslot + w*64);
#pragma unroll
    for(int j=0;j<16;j++){ float4 zz = z4[j];
      pA = fma2(mkf2(zz.x,zz.y), G2[2*j+0], pA);
      pB = fma2(mkf2(zz.z,zz.w), G2[2*j+1], pB); }
    { f2 pt = pA + pB; part[tid] = pt.x + pt.y; }
    __syncthreads();                       // barrier 1: score partials
    float s = (((part[0*64+lane]+part[1*64+lane]) + (part[2*64+lane]+part[3*64+lane]))
             + ((part[4*64+lane]+part[5*64+lane]) + (part[6*64+lane]+part[7*64+lane]))) + cst;
    s *= SCALE_;
    float mx = wred_max(s);
    float e = __expf(s - mx);
    float su = wred_sum(e);
    float att = e * __builtin_amdgcn_rcpf(su);
    attslot[tid] = att;                    // own-wave slot, no barrier
    f2 dA = mkf2(0.f,0.f), dB = mkf2(0.f,0.f);
    const float4* at4 = (const float4*)(attslot + w*64);
#pragma unroll
    for(int j=0;j<16;j++){ float4 aa = at4[j];
      dA = fma2(mkf2(aa.x,aa.y), vr2[2*j+0], dA);
      dB = fma2(mkf2(aa.z,aa.w), vr2[2*j+1], dB); }
    f2 dt = dA + dB;
    float dg = dt.x + dt.y;
    float y = z + dg;
    float s1 = wred_sum(y);
    float s2 = wred_sum(y*y);
    if(lane==0) redv[w] = make_float2(s1, s2);
    __syncthreads();                       // barrier 2: LN partials
    float S=0.f, SS=0.f;
    const float4* r4 = (const float4*)redv;
#pragma unroll
    for(int q=0;q<4;q++){ float4 rr = r4[q]; S += rr.x + rr.z; SS += rr.y + rr.w; }
    float m = S*(1.f/512.f);
    float var = (SS - S*m)*(1.f/511.f);
    float inv = __builtin_amdgcn_rcpf(sqrtf(var)+EPS_);
    z = gg*((y-m)*inv) + bb;
  }
  zfin[(size_t)b*D_ + tid] = z;
}

__global__ void k_lsm(float* __restrict__ out){
  int b = blockIdx.x; float* row = out + (size_t)b*V_;
  __shared__ float sm[16];
  int tid = threadIdx.x, lane = tid&63, wid = tid>>6;
  float mx = -3.0e38f;
  for(int i=tid;i<V_;i+=1024) mx = fmaxf(mx, row[i]);
  mx = wred_max(mx);
  if(lane==0) sm[wid] = mx;
  __syncthreads();
  float M = sm[0];
#pragma unroll
  for(int q=1;q<16;q++) M = fmaxf(M, sm[q]);
  __syncthreads();
  float s=0.f;
  for(int i=tid;i<V_;i+=1024) s += __expf(row[i]-M);
  s = wred_sum(s);
  if(lane==0) sm[wid] = s;
  __syncthreads();
  float S=0.f;
#pragma unroll
  for(int q=0;q<16;q++) S += sm[q];
  float L = M + logf(S);
  for(int i=tid;i<V_;i+=1024) row[i] -= L;
}

extern "C" void kernel_launch(void* const* d_in, const int* in_sizes, int n_in,
                              void* d_out, int out_size, void* d_ws, size_t ws_size,
                              hipStream_t stream) {
  (void)in_sizes; (void)n_in; (void)out_size; (void)ws_size;
  const int*   seq  = (const int*)d_in[0];
  const float* emb  = (const float*)d_in[2];
  const float* encK = (const float*)d_in[4];
  const float* eWq  = (const float*)d_in[5];
  const float* ebq  = (const float*)d_in[6];
  const float* eWk  = (const float*)d_in[7];
  const float* ebk  = (const float*)d_in[8];
  const float* n1g  = (const float*)d_in[9];
  const float* n1b  = (const float*)d_in[10];
  const float* rWq  = (const float*)d_in[12];
  const float* rbq  = (const float*)d_in[13];
  const float* rWk  = (const float*)d_in[14];
  const float* rbk  = (const float*)d_in[15];
  const float* rWv  = (const float*)d_in[16];
  const float* rbv  = (const float*)d_in[17];
  const float* n2g  = (const float*)d_in[22];
  const float* n2b  = (const float*)d_in[23];
  const float* vW   = (const float*)d_in[26];
  const float* vb   = (const float*)d_in[27];

  float* ws    = (float*)d_ws;
  float* x_all = ws;                                    // 16,777,216 (emb gather)
  float* av    = x_all + (size_t)SE_*B_*D_;             //  1,048,576
  float* qa    = av    + (size_t)B_*A_*D_;              //     32,768
  float* weffA = qa    + (size_t)A_*D_;                 //     32,768
  float* beff  = weffA + (size_t)A_*D_;                 //         64
  float* kr    = beff  + A_;                            //  1,048,576
  float* vr    = kr    + (size_t)B_*A_*D_;              //  1,048,576
  float* gT    = vr    + (size_t)B_*A_*D_;              //  1,048,576
  float* cst   = gT    + (size_t)B_*D_*A_;              //      2,048
  float* zfin  = cst   + (size_t)B_*A_;                 //     16,384
  float* out   = (float*)d_out;
  // zlast aliases qa: qa is only read by k_weff (dispatch 2), dead afterwards.
  float* zlast = qa;

  k_qa   <<<dim3(A_),      dim3(D_),  0, stream>>>(encK, eWq, ebq, qa);
  k_weff <<<dim3(64),      dim3(512), 0, stream>>>(qa, eWk, ebk, weffA, beff);
  k_emb  <<<dim3(8192),    dim3(256), 0, stream>>>(seq, emb, x_all);
  k_zav  <<<dim3(256),     dim3(576), 0, stream>>>(x_all, weffA, beff, n1g, n1b, av, zlast);
  k_gemm <<<dim3(8,32),    dim3(256), 0, stream>>>(av, rWk, rbk, kr, B_*A_, D_);
  k_gemm <<<dim3(8,32),    dim3(256), 0, stream>>>(av, rWv, rbv, vr, B_*A_, D_);
  k_gT2  <<<dim3(8,B_),    dim3(256), 0, stream>>>(rWq, rbq, kr, gT, cst);
  k_dec  <<<dim3(B_),      dim3(512), 0, stream>>>(gT, cst, vr, zlast, n2g, n2b, zfin);
  k_gemm <<<dim3(500,1),   dim3(256), 0, stream>>>(zfin, vW, vb, out, B_, V_);
  k_lsm  <<<dim3(B_),      dim3(1024),0, stream>>>(out);
}